// Round 1
// baseline (863.396 us; speedup 1.0000x reference)
//
#include <hip/hip_runtime.h>
#include <math.h>

#define GAT_H 4
#define GAT_HD 32
#define NDIM 128
#define EDIM 64

// ---------- tiny precompute: Ve[h][d] = sum_k W_edge[h*32+k][d] * a[h][64+k] ----------
__global__ void k_prep_ve(const float* __restrict__ We, const float* __restrict__ a,
                          float* __restrict__ Ve) {
    int tid = threadIdx.x;            // 256 threads: h = tid>>6, d = tid&63
    int h = tid >> 6, d = tid & 63;
    float s = 0.f;
#pragma unroll
    for (int k = 0; k < GAT_HD; ++k)
        s += We[(h * GAT_HD + k) * EDIM + d] * a[h * 96 + 64 + k];
    Ve[h * EDIM + d] = s;
}

// ---------- transpose W_node: Wt[k*128+c] = Wn[c*128+k] ----------
__global__ void k_transpose_w(const float* __restrict__ Wn, float* __restrict__ Wt) {
    int idx = blockIdx.x * 256 + threadIdx.x;   // 16384 total
    int c = idx >> 7, k = idx & 127;
    Wt[k * 128 + c] = Wn[c * 128 + k];
}

// ---------- node projection: h[n][c] = sum_k nf[n][k] * Wt[k][c] ----------
// 16 nodes per block, 256 threads: c = tid&127, node-group = tid>>7 (8 nodes each)
__global__ __launch_bounds__(256) void k_node_proj(const float* __restrict__ nf,
        const float* __restrict__ Wt, float* __restrict__ hout, int N) {
    __shared__ float s_nf[16][128];
    int tid = threadIdx.x;
    int n0 = blockIdx.x * 16;
    const float4* nf4 = (const float4*)(nf + (size_t)n0 * 128);
    float4* s4 = (float4*)&s_nf[0][0];
#pragma unroll
    for (int i = 0; i < 2; ++i) {
        int v = tid + i * 256;                 // 512 float4 = 16 rows
        if (n0 + (v >> 5) < N) s4[v] = nf4[v];
    }
    __syncthreads();
    int c = tid & 127;
    int g = tid >> 7;
    float acc[8];
#pragma unroll
    for (int i = 0; i < 8; ++i) acc[i] = 0.f;
    for (int k = 0; k < 128; k += 4) {
        float w0 = Wt[(k + 0) * 128 + c];
        float w1 = Wt[(k + 1) * 128 + c];
        float w2 = Wt[(k + 2) * 128 + c];
        float w3 = Wt[(k + 3) * 128 + c];
#pragma unroll
        for (int i = 0; i < 8; ++i) {
            float4 x = *(const float4*)&s_nf[g * 8 + i][k];
            acc[i] += x.x * w0 + x.y * w1 + x.z * w2 + x.w * w3;
        }
    }
#pragma unroll
    for (int i = 0; i < 8; ++i) {
        int n = n0 + g * 8 + i;
        if (n < N) hout[(size_t)n * 128 + c] = acc[i];
    }
}

// ---------- alpha_src/alpha_tgt: per (node, head) dot of h slice with a ----------
__global__ void k_alpha(const float* __restrict__ hmat, const float* __restrict__ a,
                        float* __restrict__ asrc, float* __restrict__ atgt, int N) {
    int idx = blockIdx.x * 256 + threadIdx.x;
    if (idx >= N * GAT_H) return;
    int n = idx >> 2, head = idx & 3;
    const float* hp = hmat + (size_t)n * 128 + head * 32;
    const float* ap = a + head * 96;
    float s = 0.f, t = 0.f;
#pragma unroll
    for (int d = 0; d < 32; d += 4) {
        float4 hv = *(const float4*)(hp + d);
        float4 a0 = *(const float4*)(ap + d);
        float4 a1 = *(const float4*)(ap + 32 + d);
        s += hv.x * a0.x + hv.y * a0.y + hv.z * a0.z + hv.w * a0.w;
        t += hv.x * a1.x + hv.y * a1.y + hv.z * a1.z + hv.w * a1.w;
    }
    asrc[idx] = s;
    atgt[idx] = t;
}

// ---------- per-edge attention logit + segment max (int-punned atomicMax) ----------
__global__ void k_edge_att(const int* __restrict__ ei, const float* __restrict__ ef,
        const float* __restrict__ Ve, const float* __restrict__ asrc,
        const float* __restrict__ atgt, float* __restrict__ att,
        float* __restrict__ m, int* __restrict__ deg, int E) {
    __shared__ float sVe[GAT_H * EDIM];
    if (threadIdx.x < GAT_H * EDIM) sVe[threadIdx.x] = Ve[threadIdx.x];
    __syncthreads();
    int e = blockIdx.x * 256 + threadIdx.x;
    if (e >= E) return;
    int s = ei[e], t = ei[E + e];
    float ae0 = 0.f, ae1 = 0.f, ae2 = 0.f, ae3 = 0.f;
    const float* ep = ef + (size_t)e * EDIM;
#pragma unroll
    for (int d = 0; d < EDIM; d += 4) {
        float4 x = *(const float4*)(ep + d);
        const float* v0 = sVe + 0 * EDIM + d;
        const float* v1 = sVe + 1 * EDIM + d;
        const float* v2 = sVe + 2 * EDIM + d;
        const float* v3 = sVe + 3 * EDIM + d;
        ae0 += x.x * v0[0] + x.y * v0[1] + x.z * v0[2] + x.w * v0[3];
        ae1 += x.x * v1[0] + x.y * v1[1] + x.z * v1[2] + x.w * v1[3];
        ae2 += x.x * v2[0] + x.y * v2[1] + x.z * v2[2] + x.w * v2[3];
        ae3 += x.x * v3[0] + x.y * v3[1] + x.z * v3[2] + x.w * v3[3];
    }
    float4 as4 = *(const float4*)(asrc + (size_t)s * 4);
    float4 at4 = *(const float4*)(atgt + (size_t)t * 4);
    float av[4] = { as4.x + at4.x + ae0, as4.y + at4.y + ae1,
                    as4.z + at4.z + ae2, as4.w + at4.w + ae3 };
    float4 o;
    float* ov = (float*)&o;
#pragma unroll
    for (int h = 0; h < GAT_H; ++h) {
        float v = av[h];
        v = v > 0.f ? v : 0.2f * v;           // LeakyReLU(0.2)
        ov[h] = v;
        // segment max, clamped below at 0: only positive values can matter,
        // and positive IEEE floats order like their int bit patterns.
        if (v > 0.f) atomicMax((int*)&m[(size_t)t * 4 + h], __float_as_int(v));
    }
    *(float4*)(att + (size_t)e * 4) = o;
    atomicAdd(&deg[t], 1);
}

// ---------- ex = exp(att - m[tgt]); partial denom sums ----------
__global__ void k_edge_ex(const int* __restrict__ ei, const float* __restrict__ m,
        float* __restrict__ att, float* __restrict__ dsum, int E) {
    int e = blockIdx.x * 256 + threadIdx.x;
    if (e >= E) return;
    int t = ei[E + e];
    float4 av = *(const float4*)(att + (size_t)e * 4);
    float4 mv = *(const float4*)(m + (size_t)t * 4);
    float4 ex;
    ex.x = expf(av.x - mv.x);
    ex.y = expf(av.y - mv.y);
    ex.z = expf(av.z - mv.z);
    ex.w = expf(av.w - mv.w);
    *(float4*)(att + (size_t)e * 4) = ex;     // overwrite att buffer with ex
    atomicAdd(&dsum[(size_t)t * 4 + 0], ex.x);
    atomicAdd(&dsum[(size_t)t * 4 + 1], ex.y);
    atomicAdd(&dsum[(size_t)t * 4 + 2], ex.z);
    atomicAdd(&dsum[(size_t)t * 4 + 3], ex.w);
}

// ---------- finalize denom: += (E - deg) * exp(-m) ----------
__global__ void k_denom(const float* __restrict__ m, const int* __restrict__ deg,
        float* __restrict__ dsum, int N, float Ef) {
    int n = blockIdx.x * 256 + threadIdx.x;
    if (n >= N) return;
    float4 mv = *(const float4*)(m + (size_t)n * 4);
    float4 dv = *(const float4*)(dsum + (size_t)n * 4);
    float rem = Ef - (float)deg[n];
    dv.x += rem * expf(-mv.x);
    dv.y += rem * expf(-mv.y);
    dv.z += rem * expf(-mv.z);
    dv.w += rem * expf(-mv.w);
    *(float4*)(dsum + (size_t)n * 4) = dv;
}

// ---------- aggregate: out[tgt] += (ex/denom[tgt]) * h[src], 128 threads/edge ----------
__global__ __launch_bounds__(256) void k_aggregate(const int* __restrict__ ei,
        const float* __restrict__ ex, const float* __restrict__ denom,
        const float* __restrict__ hmat, float* __restrict__ out, int E) {
    int tid = threadIdx.x;
    int e = blockIdx.x * 2 + (tid >> 7);
    if (e >= E) return;
    int c = tid & 127;
    int head = c >> 5;
    int s = ei[e], t = ei[E + e];
    float w = ex[(size_t)e * 4 + head] / denom[(size_t)t * 4 + head];
    atomicAdd(out + (size_t)t * 128 + c, w * hmat[(size_t)s * 128 + c]);
}

extern "C" void kernel_launch(void* const* d_in, const int* in_sizes, int n_in,
                              void* d_out, int out_size, void* d_ws, size_t ws_size,
                              hipStream_t stream) {
    const float* nf = (const float*)d_in[0];
    const int*   ei = (const int*)d_in[1];
    const float* ef = (const float*)d_in[2];
    const float* Wn = (const float*)d_in[3];
    const float* We = (const float*)d_in[4];
    const float* a  = (const float*)d_in[5];
    int N = in_sizes[0] / 128;
    int E = in_sizes[1] / 2;
    float* out = (float*)d_out;

    // workspace layout (floats)
    float* ws   = (float*)d_ws;
    float* hmat = ws;                            // N*128
    float* Wt   = hmat + (size_t)N * 128;        // 16384
    float* asrc = Wt + 16384;                    // N*4
    float* atgt = asrc + (size_t)N * 4;          // N*4
    float* Ve   = atgt + (size_t)N * 4;          // 256
    float* att  = Ve + 256;                      // E*4 (becomes ex)
    float* m    = att + (size_t)E * 4;           // N*4
    float* dsum = m + (size_t)N * 4;             // N*4 (becomes denom)
    int*   deg  = (int*)(dsum + (size_t)N * 4);  // N

    hipMemsetAsync(m,    0, (size_t)N * 4 * sizeof(float), stream);
    hipMemsetAsync(dsum, 0, (size_t)N * 4 * sizeof(float), stream);
    hipMemsetAsync(deg,  0, (size_t)N * sizeof(int), stream);
    hipMemsetAsync(out,  0, (size_t)N * 128 * sizeof(float), stream);

    k_prep_ve<<<1, 256, 0, stream>>>(We, a, Ve);
    k_transpose_w<<<64, 256, 0, stream>>>(Wn, Wt);
    k_node_proj<<<(N + 15) / 16, 256, 0, stream>>>(nf, Wt, hmat, N);
    k_alpha<<<(N * GAT_H + 255) / 256, 256, 0, stream>>>(hmat, a, asrc, atgt, N);
    k_edge_att<<<(E + 255) / 256, 256, 0, stream>>>(ei, ef, Ve, asrc, atgt, att, m, deg, E);
    k_edge_ex<<<(E + 255) / 256, 256, 0, stream>>>(ei, m, att, dsum, E);
    k_denom<<<(N + 255) / 256, 256, 0, stream>>>(m, deg, dsum, N, (float)E);
    k_aggregate<<<(E + 1) / 2, 256, 0, stream>>>(ei, att, dsum, hmat, out, E);
}

// Round 3
// 633.089 us; speedup vs baseline: 1.3638x; 1.3638x over previous
//
#include <hip/hip_runtime.h>
#include <math.h>

#define GAT_H 4
#define GAT_HD 32
#define NDIM 128
#define EDIM 64

// ---------- tiny precompute: Ve[h][d] = sum_k W_edge[h*32+k][d] * a[h][64+k] ----------
__global__ void k_prep_ve(const float* __restrict__ We, const float* __restrict__ a,
                          float* __restrict__ Ve) {
    int tid = threadIdx.x;            // 256 threads: h = tid>>6, d = tid&63
    int h = tid >> 6, d = tid & 63;
    float s = 0.f;
#pragma unroll
    for (int k = 0; k < GAT_HD; ++k)
        s += We[(h * GAT_HD + k) * EDIM + d] * a[h * 96 + 64 + k];
    Ve[h * EDIM + d] = s;
}

// ---------- transpose W_node: Wt[k*128+c] = Wn[c*128+k] ----------
__global__ void k_transpose_w(const float* __restrict__ Wn, float* __restrict__ Wt) {
    int idx = blockIdx.x * 256 + threadIdx.x;   // 16384 total
    int c = idx >> 7, k = idx & 127;
    Wt[k * 128 + c] = Wn[c * 128 + k];
}

// ---------- node projection: h[n][c] = sum_k nf[n][k] * Wt[k][c] ----------
__global__ __launch_bounds__(256) void k_node_proj(const float* __restrict__ nf,
        const float* __restrict__ Wt, float* __restrict__ hout, int N) {
    __shared__ float s_nf[16][128];
    int tid = threadIdx.x;
    int n0 = blockIdx.x * 16;
    const float4* nf4 = (const float4*)(nf + (size_t)n0 * 128);
    float4* s4 = (float4*)&s_nf[0][0];
#pragma unroll
    for (int i = 0; i < 2; ++i) {
        int v = tid + i * 256;                 // 512 float4 = 16 rows
        if (n0 + (v >> 5) < N) s4[v] = nf4[v];
    }
    __syncthreads();
    int c = tid & 127;
    int g = tid >> 7;
    float acc[8];
#pragma unroll
    for (int i = 0; i < 8; ++i) acc[i] = 0.f;
    for (int k = 0; k < 128; k += 4) {
        float w0 = Wt[(k + 0) * 128 + c];
        float w1 = Wt[(k + 1) * 128 + c];
        float w2 = Wt[(k + 2) * 128 + c];
        float w3 = Wt[(k + 3) * 128 + c];
#pragma unroll
        for (int i = 0; i < 8; ++i) {
            float4 x = *(const float4*)&s_nf[g * 8 + i][k];
            acc[i] += x.x * w0 + x.y * w1 + x.z * w2 + x.w * w3;
        }
    }
#pragma unroll
    for (int i = 0; i < 8; ++i) {
        int n = n0 + g * 8 + i;
        if (n < N) hout[(size_t)n * 128 + c] = acc[i];
    }
}

// ---------- alpha_src/alpha_tgt: per (node, head) dot of h slice with a ----------
__global__ void k_alpha(const float* __restrict__ hmat, const float* __restrict__ a,
                        float* __restrict__ asrc, float* __restrict__ atgt, int N) {
    int idx = blockIdx.x * 256 + threadIdx.x;
    if (idx >= N * GAT_H) return;
    int n = idx >> 2, head = idx & 3;
    const float* hp = hmat + (size_t)n * 128 + head * 32;
    const float* ap = a + head * 96;
    float s = 0.f, t = 0.f;
#pragma unroll
    for (int d = 0; d < 32; d += 4) {
        float4 hv = *(const float4*)(hp + d);
        float4 a0 = *(const float4*)(ap + d);
        float4 a1 = *(const float4*)(ap + 32 + d);
        s += hv.x * a0.x + hv.y * a0.y + hv.z * a0.z + hv.w * a0.w;
        t += hv.x * a1.x + hv.y * a1.y + hv.z * a1.z + hv.w * a1.w;
    }
    asrc[idx] = s;
    atgt[idx] = t;
}

// ---------- degree count ----------
__global__ void k_deg(const int* __restrict__ ei, int* __restrict__ deg, int E) {
    int e = blockIdx.x * 256 + threadIdx.x;
    if (e < E) atomicAdd(&deg[ei[E + e]], 1);
}

// ---------- exclusive scan of deg -> off[0..N], single block of 1024 ----------
__global__ __launch_bounds__(1024) void k_scan(const int* __restrict__ deg,
                                               int* __restrict__ off, int N) {
    __shared__ int s[1024];
    int tid = threadIdx.x;
    int chunk = (N + 1023) >> 10;
    int lo = tid * chunk, hi = min(lo + chunk, N);
    int sum = 0;
    for (int i = lo; i < hi; ++i) sum += deg[i];
    s[tid] = sum;
    __syncthreads();
    for (int d = 1; d < 1024; d <<= 1) {
        int v = (tid >= d) ? s[tid - d] : 0;
        __syncthreads();
        s[tid] += v;
        __syncthreads();
    }
    int run = s[tid] - sum;              // exclusive prefix of this chunk
    for (int i = lo; i < hi; ++i) { off[i] = run; run += deg[i]; }
    if (tid == 1023) off[N] = s[1023];
}

// ---------- edge logits + scatter into CSR slots ----------
__global__ void k_edge_att_scatter(const int* __restrict__ ei, const float* __restrict__ ef,
        const float* __restrict__ Ve, const float* __restrict__ asrc,
        const float* __restrict__ atgt, const int* __restrict__ off,
        int* __restrict__ cursor, int* __restrict__ ssrc, float4* __restrict__ satt, int E) {
    __shared__ float sVe[GAT_H * EDIM];
    if (threadIdx.x < GAT_H * EDIM) sVe[threadIdx.x] = Ve[threadIdx.x];
    __syncthreads();
    int e = blockIdx.x * 256 + threadIdx.x;
    if (e >= E) return;
    int s = ei[e], t = ei[E + e];
    float ae0 = 0.f, ae1 = 0.f, ae2 = 0.f, ae3 = 0.f;
    const float* ep = ef + (size_t)e * EDIM;
#pragma unroll
    for (int d = 0; d < EDIM; d += 4) {
        float4 x = *(const float4*)(ep + d);
        const float* v0 = sVe + 0 * EDIM + d;
        const float* v1 = sVe + 1 * EDIM + d;
        const float* v2 = sVe + 2 * EDIM + d;
        const float* v3 = sVe + 3 * EDIM + d;
        ae0 += x.x * v0[0] + x.y * v0[1] + x.z * v0[2] + x.w * v0[3];
        ae1 += x.x * v1[0] + x.y * v1[1] + x.z * v1[2] + x.w * v1[3];
        ae2 += x.x * v2[0] + x.y * v2[1] + x.z * v2[2] + x.w * v2[3];
        ae3 += x.x * v3[0] + x.y * v3[1] + x.z * v3[2] + x.w * v3[3];
    }
    float4 as4 = *(const float4*)(asrc + (size_t)s * 4);
    float4 at4 = *(const float4*)(atgt + (size_t)t * 4);
    float av[4] = { as4.x + at4.x + ae0, as4.y + at4.y + ae1,
                    as4.z + at4.z + ae2, as4.w + at4.w + ae3 };
    float4 o;
    float* ov = (float*)&o;
#pragma unroll
    for (int h = 0; h < GAT_H; ++h) {
        float v = av[h];
        ov[h] = v > 0.f ? v : 0.2f * v;       // LeakyReLU(0.2)
    }
    int slot = off[t] + atomicAdd(&cursor[t], 1);
    ssrc[slot] = s;
    satt[slot] = o;
}

// ---------- fused per-node: segment max, denom, weighted aggregate ----------
// one wave (64 lanes) per node; lane covers output cols [2*lane, 2*lane+1]
__global__ __launch_bounds__(256) void k_node_agg(const int* __restrict__ off,
        const int* __restrict__ ssrc, const float4* __restrict__ satt,
        const float* __restrict__ hmat, float* __restrict__ out, int N, float Ef) {
    int n = (blockIdx.x * 256 + threadIdx.x) >> 6;
    if (n >= N) return;
    int lane = threadIdx.x & 63;
    int o0 = off[n], o1 = off[n + 1];
    // pass 1: per-head running max, clamped below at 0 (matches ref max(segmax, 0))
    float m0 = 0.f, m1 = 0.f, m2 = 0.f, m3 = 0.f;
    for (int j = o0; j < o1; ++j) {
        float4 v = satt[j];
        m0 = fmaxf(m0, v.x); m1 = fmaxf(m1, v.y);
        m2 = fmaxf(m2, v.z); m3 = fmaxf(m3, v.w);
    }
    // pass 2: denominator = sum exp(att-m) + (E-deg)*exp(-m)
    float rem = Ef - (float)(o1 - o0);
    float d0 = rem * expf(-m0), d1 = rem * expf(-m1),
          d2 = rem * expf(-m2), d3 = rem * expf(-m3);
    for (int j = o0; j < o1; ++j) {
        float4 v = satt[j];
        d0 += expf(v.x - m0); d1 += expf(v.y - m1);
        d2 += expf(v.z - m2); d3 += expf(v.w - m3);
    }
    int head = lane >> 4;                     // cols 2*lane,2*lane+1 share one head
    float mh = head < 2 ? (head == 0 ? m0 : m1) : (head == 2 ? m2 : m3);
    float dh = head < 2 ? (head == 0 ? d0 : d1) : (head == 2 ? d2 : d3);
    float rdh = 1.f / dh;
    // pass 3: accumulate w * h[src]
    float accx = 0.f, accy = 0.f;
    for (int j = o0; j < o1; ++j) {
        float4 v = satt[j];
        float av = head < 2 ? (head == 0 ? v.x : v.y) : (head == 2 ? v.z : v.w);
        float w = expf(av - mh) * rdh;
        float2 hv = ((const float2*)(hmat + (size_t)ssrc[j] * 128))[lane];
        accx += w * hv.x; accy += w * hv.y;
    }
    float2 o2; o2.x = accx; o2.y = accy;
    ((float2*)(out + (size_t)n * 128))[lane] = o2;
}

extern "C" void kernel_launch(void* const* d_in, const int* in_sizes, int n_in,
                              void* d_out, int out_size, void* d_ws, size_t ws_size,
                              hipStream_t stream) {
    const float* nf = (const float*)d_in[0];
    const int*   ei = (const int*)d_in[1];
    const float* ef = (const float*)d_in[2];
    const float* Wn = (const float*)d_in[3];
    const float* We = (const float*)d_in[4];
    const float* a  = (const float*)d_in[5];
    int N = in_sizes[0] / 128;
    int E = in_sizes[1] / 2;
    float* out = (float*)d_out;

    // workspace layout (floats / ints, all 16B-aligned offsets)
    float* ws   = (float*)d_ws;
    float* hmat = ws;                              // N*128
    float* Wt   = hmat + (size_t)N * 128;          // 16384
    float* asrc = Wt + 16384;                      // N*4
    float* atgt = asrc + (size_t)N * 4;            // N*4
    float* Ve   = atgt + (size_t)N * 4;            // 256
    float4* satt = (float4*)(Ve + 256);            // E float4
    int* ssrc   = (int*)(satt + (size_t)E);        // E
    int* off    = ssrc + (size_t)E;                // N+1
    int* deg    = off + (size_t)N + 4;             // N  (+4 pad keeps alignment)
    int* cursor = deg + (size_t)N;                 // N

    hipMemsetAsync(deg,    0, (size_t)N * sizeof(int), stream);
    hipMemsetAsync(cursor, 0, (size_t)N * sizeof(int), stream);

    k_prep_ve<<<1, 256, 0, stream>>>(We, a, Ve);
    k_transpose_w<<<64, 256, 0, stream>>>(Wn, Wt);
    k_node_proj<<<(N + 15) / 16, 256, 0, stream>>>(nf, Wt, hmat, N);
    k_alpha<<<(N * GAT_H + 255) / 256, 256, 0, stream>>>(hmat, a, asrc, atgt, N);
    k_deg<<<(E + 255) / 256, 256, 0, stream>>>(ei, deg, E);
    k_scan<<<1, 1024, 0, stream>>>(deg, off, N);
    k_edge_att_scatter<<<(E + 255) / 256, 256, 0, stream>>>(ei, ef, Ve, asrc, atgt,
                                                            off, cursor, ssrc, satt, E);
    k_node_agg<<<(N * 64 + 255) / 256, 256, 0, stream>>>(off, ssrc, satt, hmat, out,
                                                         N, (float)E);
}

// Round 6
// 543.139 us; speedup vs baseline: 1.5896x; 1.1656x over previous
//
#include <hip/hip_runtime.h>
#include <math.h>

#define GAT_H 4
#define GAT_HD 32
#define NDIM 128
#define EDIM 64

// ---------- fused setup: block 0 = Ve precompute, blocks 1..64 = W transpose,
// ---------- blocks 65.. = degree count ----------
__global__ void k_setup(const float* __restrict__ We, const float* __restrict__ a,
                        float* __restrict__ Ve, const float* __restrict__ Wn,
                        float* __restrict__ Wt, const int* __restrict__ ei,
                        int* __restrict__ deg, int E) {
    int b = blockIdx.x, tid = threadIdx.x;
    if (b == 0) {
        int h = tid >> 6, d = tid & 63;
        float s = 0.f;
#pragma unroll
        for (int k = 0; k < GAT_HD; ++k)
            s += We[(h * GAT_HD + k) * EDIM + d] * a[h * 96 + 64 + k];
        Ve[h * EDIM + d] = s;
    } else if (b <= 64) {
        int idx = (b - 1) * 256 + tid;         // 16384 total
        int c = idx >> 7, k = idx & 127;
        Wt[k * 128 + c] = Wn[c * 128 + k];
    } else {
        int e = (b - 65) * 256 + tid;
        if (e < E) atomicAdd(&deg[ei[E + e]], 1);
    }
}

// ---------- node projection: h[n][c] = sum_k nf[n][k] * Wt[k][c] ----------
__global__ __launch_bounds__(256) void k_node_proj(const float* __restrict__ nf,
        const float* __restrict__ Wt, float* __restrict__ hout, int N) {
    __shared__ float s_nf[16][128];
    int tid = threadIdx.x;
    int n0 = blockIdx.x * 16;
    const float4* nf4 = (const float4*)(nf + (size_t)n0 * 128);
    float4* s4 = (float4*)&s_nf[0][0];
#pragma unroll
    for (int i = 0; i < 2; ++i) {
        int v = tid + i * 256;                 // 512 float4 = 16 rows
        if (n0 + (v >> 5) < N) s4[v] = nf4[v];
    }
    __syncthreads();
    int c = tid & 127;
    int g = tid >> 7;
    float acc[8];
#pragma unroll
    for (int i = 0; i < 8; ++i) acc[i] = 0.f;
    for (int k = 0; k < 128; k += 4) {
        float w0 = Wt[(k + 0) * 128 + c];
        float w1 = Wt[(k + 1) * 128 + c];
        float w2 = Wt[(k + 2) * 128 + c];
        float w3 = Wt[(k + 3) * 128 + c];
#pragma unroll
        for (int i = 0; i < 8; ++i) {
            float4 x = *(const float4*)&s_nf[g * 8 + i][k];
            acc[i] += x.x * w0 + x.y * w1 + x.z * w2 + x.w * w3;
        }
    }
#pragma unroll
    for (int i = 0; i < 8; ++i) {
        int n = n0 + g * 8 + i;
        if (n < N) hout[(size_t)n * 128 + c] = acc[i];
    }
}

// ---------- alpha_src/alpha_tgt: per (node, head) dot of h slice with a ----------
__global__ void k_alpha(const float* __restrict__ hmat, const float* __restrict__ a,
                        float* __restrict__ asrc, float* __restrict__ atgt, int N) {
    int idx = blockIdx.x * 256 + threadIdx.x;
    if (idx >= N * GAT_H) return;
    int n = idx >> 2, head = idx & 3;
    const float* hp = hmat + (size_t)n * 128 + head * 32;
    const float* ap = a + head * 96;
    float s = 0.f, t = 0.f;
#pragma unroll
    for (int d = 0; d < 32; d += 4) {
        float4 hv = *(const float4*)(hp + d);
        float4 a0 = *(const float4*)(ap + d);
        float4 a1 = *(const float4*)(ap + 32 + d);
        s += hv.x * a0.x + hv.y * a0.y + hv.z * a0.z + hv.w * a0.w;
        t += hv.x * a1.x + hv.y * a1.y + hv.z * a1.z + hv.w * a1.w;
    }
    asrc[idx] = s;
    atgt[idx] = t;
}

// ---------- exclusive scan of deg -> off[0..N]; also zero cursor ----------
__global__ __launch_bounds__(1024) void k_scan(const int* __restrict__ deg,
                                               int* __restrict__ off,
                                               int* __restrict__ cursor, int N) {
    __shared__ int s[1024];
    int tid = threadIdx.x;
    int chunk = (N + 1023) >> 10;
    int lo = tid * chunk, hi = min(lo + chunk, N);
    int sum = 0;
    for (int i = lo; i < hi; ++i) sum += deg[i];
    s[tid] = sum;
    __syncthreads();
    for (int d = 1; d < 1024; d <<= 1) {
        int v = (tid >= d) ? s[tid - d] : 0;
        __syncthreads();
        s[tid] += v;
        __syncthreads();
    }
    int run = s[tid] - sum;              // exclusive prefix of this chunk
    for (int i = lo; i < hi; ++i) { off[i] = run; run += deg[i]; cursor[i] = 0; }
    if (tid == 1023) off[N] = s[1023];
}

// ---------- edge logits + scatter into CSR slots ----------
__global__ void k_edge_att_scatter(const int* __restrict__ ei, const float* __restrict__ ef,
        const float* __restrict__ Ve, const float* __restrict__ asrc,
        const float* __restrict__ atgt, const int* __restrict__ off,
        int* __restrict__ cursor, int* __restrict__ ssrc, float4* __restrict__ satt, int E) {
    __shared__ float sVe[GAT_H * EDIM];
    if (threadIdx.x < GAT_H * EDIM) sVe[threadIdx.x] = Ve[threadIdx.x];
    __syncthreads();
    int e = blockIdx.x * 256 + threadIdx.x;
    if (e >= E) return;
    int s = ei[e], t = ei[E + e];
    float ae0 = 0.f, ae1 = 0.f, ae2 = 0.f, ae3 = 0.f;
    const float* ep = ef + (size_t)e * EDIM;
#pragma unroll
    for (int d = 0; d < EDIM; d += 4) {
        float4 x = *(const float4*)(ep + d);
        const float* v0 = sVe + 0 * EDIM + d;
        const float* v1 = sVe + 1 * EDIM + d;
        const float* v2 = sVe + 2 * EDIM + d;
        const float* v3 = sVe + 3 * EDIM + d;
        ae0 += x.x * v0[0] + x.y * v0[1] + x.z * v0[2] + x.w * v0[3];
        ae1 += x.x * v1[0] + x.y * v1[1] + x.z * v1[2] + x.w * v1[3];
        ae2 += x.x * v2[0] + x.y * v2[1] + x.z * v2[2] + x.w * v2[3];
        ae3 += x.x * v3[0] + x.y * v3[1] + x.z * v3[2] + x.w * v3[3];
    }
    float4 as4 = *(const float4*)(asrc + (size_t)s * 4);
    float4 at4 = *(const float4*)(atgt + (size_t)t * 4);
    float av[4] = { as4.x + at4.x + ae0, as4.y + at4.y + ae1,
                    as4.z + at4.z + ae2, as4.w + at4.w + ae3 };
    float4 o;
    float* ov = (float*)&o;
#pragma unroll
    for (int h = 0; h < GAT_H; ++h) {
        float v = av[h];
        ov[h] = v > 0.f ? v : 0.2f * v;       // LeakyReLU(0.2)
    }
    int slot = off[t] + atomicAdd(&cursor[t], 1);
    ssrc[slot] = s;
    satt[slot] = o;
}

// ---------- fused per-node softmax + aggregate, one wave per node ----------
// Phase A: lane-parallel max (+shfl reduce). Phase B: lane-parallel exp/denom,
// store ex back to satt. Phase C: per-lane 2 output cols, unroll-4 gathers.
__global__ __launch_bounds__(256) void k_node_agg(const int* __restrict__ off,
        const int* __restrict__ ssrc, float4* __restrict__ satt,
        const float* __restrict__ hmat, float* __restrict__ out, int N, float Ef) {
    int n = (blockIdx.x * 256 + threadIdx.x) >> 6;
    if (n >= N) return;
    int lane = threadIdx.x & 63;
    int o0 = __builtin_amdgcn_readfirstlane(off[n]);
    int o1 = __builtin_amdgcn_readfirstlane(off[n + 1]);
    int deg = o1 - o0;

    // ---- phase A: per-head max, clamped below at 0 ----
    float m0 = 0.f, m1 = 0.f, m2 = 0.f, m3 = 0.f;
    for (int j = o0 + lane; j < o1; j += 64) {
        float4 v = satt[j];
        m0 = fmaxf(m0, v.x); m1 = fmaxf(m1, v.y);
        m2 = fmaxf(m2, v.z); m3 = fmaxf(m3, v.w);
    }
#pragma unroll
    for (int d = 32; d > 0; d >>= 1) {
        m0 = fmaxf(m0, __shfl_xor(m0, d));
        m1 = fmaxf(m1, __shfl_xor(m1, d));
        m2 = fmaxf(m2, __shfl_xor(m2, d));
        m3 = fmaxf(m3, __shfl_xor(m3, d));
    }

    // ---- phase B: ex = exp(att-m), partial denoms, store ex back ----
    float d0 = 0.f, d1 = 0.f, d2 = 0.f, d3 = 0.f;
    for (int j = o0 + lane; j < o1; j += 64) {
        float4 v = satt[j];
        float4 ex;
        ex.x = __expf(v.x - m0); ex.y = __expf(v.y - m1);
        ex.z = __expf(v.z - m2); ex.w = __expf(v.w - m3);
        d0 += ex.x; d1 += ex.y; d2 += ex.z; d3 += ex.w;
        satt[j] = ex;
    }
#pragma unroll
    for (int d = 32; d > 0; d >>= 1) {
        d0 += __shfl_xor(d0, d);
        d1 += __shfl_xor(d1, d);
        d2 += __shfl_xor(d2, d);
        d3 += __shfl_xor(d3, d);
    }
    float rem = Ef - (float)deg;
    d0 += rem * __expf(-m0); d1 += rem * __expf(-m1);
    d2 += rem * __expf(-m2); d3 += rem * __expf(-m3);

    int head = lane >> 4;
    float dh = head < 2 ? (head == 0 ? d0 : d1) : (head == 2 ? d2 : d3);
    float rdh = 1.f / dh;

    // ---- phase C: accumulate w * h[src], 2 cols per lane, unroll 4 ----
    const float2* hm2 = (const float2*)hmat;
    float accx = 0.f, accy = 0.f;
    int j = o0;
    for (; j + 3 < o1; j += 4) {
        float4 e0 = satt[j + 0], e1 = satt[j + 1];
        float4 e2 = satt[j + 2], e3 = satt[j + 3];
        int s0 = ssrc[j + 0], s1 = ssrc[j + 1];
        int s2 = ssrc[j + 2], s3 = ssrc[j + 3];
        float2 h0 = hm2[(size_t)s0 * 64 + lane];
        float2 h1 = hm2[(size_t)s1 * 64 + lane];
        float2 h2 = hm2[(size_t)s2 * 64 + lane];
        float2 h3 = hm2[(size_t)s3 * 64 + lane];
        float w0 = (head < 2 ? (head == 0 ? e0.x : e0.y) : (head == 2 ? e0.z : e0.w)) * rdh;
        float w1 = (head < 2 ? (head == 0 ? e1.x : e1.y) : (head == 2 ? e1.z : e1.w)) * rdh;
        float w2 = (head < 2 ? (head == 0 ? e2.x : e2.y) : (head == 2 ? e2.z : e2.w)) * rdh;
        float w3 = (head < 2 ? (head == 0 ? e3.x : e3.y) : (head == 2 ? e3.z : e3.w)) * rdh;
        accx += w0 * h0.x; accy += w0 * h0.y;
        accx += w1 * h1.x; accy += w1 * h1.y;
        accx += w2 * h2.x; accy += w2 * h2.y;
        accx += w3 * h3.x; accy += w3 * h3.y;
    }
    for (; j < o1; ++j) {
        float4 e0 = satt[j];
        int s0 = ssrc[j];
        float2 h0 = hm2[(size_t)s0 * 64 + lane];
        float w0 = (head < 2 ? (head == 0 ? e0.x : e0.y) : (head == 2 ? e0.z : e0.w)) * rdh;
        accx += w0 * h0.x; accy += w0 * h0.y;
    }
    float2 o2; o2.x = accx; o2.y = accy;
    ((float2*)out)[(size_t)n * 64 + lane] = o2;
}

extern "C" void kernel_launch(void* const* d_in, const int* in_sizes, int n_in,
                              void* d_out, int out_size, void* d_ws, size_t ws_size,
                              hipStream_t stream) {
    const float* nf = (const float*)d_in[0];
    const int*   ei = (const int*)d_in[1];
    const float* ef = (const float*)d_in[2];
    const float* Wn = (const float*)d_in[3];
    const float* We = (const float*)d_in[4];
    const float* a  = (const float*)d_in[5];
    int N = in_sizes[0] / 128;
    int E = in_sizes[1] / 2;
    float* out = (float*)d_out;

    // workspace layout (floats / ints, all 16B-aligned offsets)
    float* ws   = (float*)d_ws;
    float* hmat = ws;                              // N*128
    float* Wt   = hmat + (size_t)N * 128;          // 16384
    float* asrc = Wt + 16384;                      // N*4
    float* atgt = asrc + (size_t)N * 4;            // N*4
    float* Ve   = atgt + (size_t)N * 4;            // 256
    float4* satt = (float4*)(Ve + 256);            // E float4
    int* ssrc   = (int*)(satt + (size_t)E);        // E
    int* off    = ssrc + (size_t)E;                // N+1
    int* deg    = off + (size_t)N + 4;             // N  (+4 pad keeps alignment)
    int* cursor = deg + (size_t)N;                 // N

    hipMemsetAsync(deg, 0, (size_t)N * sizeof(int), stream);

    int degBlocks = (E + 255) / 256;
    k_setup<<<65 + degBlocks, 256, 0, stream>>>(We, a, Ve, Wn, Wt, ei, deg, E);
    k_node_proj<<<(N + 15) / 16, 256, 0, stream>>>(nf, Wt, hmat, N);
    k_alpha<<<(N * GAT_H + 255) / 256, 256, 0, stream>>>(hmat, a, asrc, atgt, N);
    k_scan<<<1, 1024, 0, stream>>>(deg, off, cursor, N);
    k_edge_att_scatter<<<(E + 255) / 256, 256, 0, stream>>>(ei, ef, Ve, asrc, atgt,
                                                            off, cursor, ssrc, satt, E);
    k_node_agg<<<(N * 64 + 255) / 256, 256, 0, stream>>>(off, ssrc, satt, hmat, out,
                                                         N, (float)E);
}